// Round 2
// baseline (53.244 us; speedup 1.0000x reference)
//
#include <hip/hip_runtime.h>

#define NJ 24
#define BLK 128
#define STRIDE 27            // LDS columns per row (max phase width), odd -> conflict-free
#define OUTW 75              // (NJ+1)*3 floats per output row

// Copy a BLK x LEN column-slice from LDS (stride STRIDE) to global rows of
// width OUTW at column offset GOFF. Scalar stores, contiguous LEN-float runs
// per row -> L2 write-combines to full lines.
template<int LEN, int GOFF>
__device__ inline void dump_phase(const float* __restrict__ buf,
                                  float* __restrict__ gout) {
    #pragma unroll
    for (int k = 0; k < LEN; ++k) {
        int i = k * BLK + threadIdx.x;
        int r = i / LEN, c = i - r * LEN;       // LEN is compile-time -> magic mul
        gout[r * OUTW + GOFF + c] = buf[r * STRIDE + c];
    }
}

__global__ __launch_bounds__(BLK, 4) void fk_main_kernel(
    const float* __restrict__ ang,   // (B, 24)
    const float* __restrict__ xyz,   // (24, 3)
    const float* __restrict__ rpy,   // (24, 3)
    const float* __restrict__ axis,  // (24, 3)
    float* __restrict__ out)         // (B, 75)
{
    __shared__ float lcst[NJ * 16];        // per joint: Ro[9], xyz[3], u[3], |axis|
    __shared__ float buf[BLK * STRIDE];    // phased output staging (15.4 KB total LDS)

    const int tid = threadIdx.x;
    const long long b0 = (long long)blockIdx.x * BLK;

    // ---- my row's 24 angles via 6x float4 (row base 96B -> 16B aligned) ----
    const float4* gA4 = (const float4*)(ang + (b0 + tid) * NJ);
    float4 a0 = gA4[0], a1 = gA4[1], a2 = gA4[2], a3 = gA4[3], a4 = gA4[4], a5 = gA4[5];
    float th[NJ] = {a0.x,a0.y,a0.z,a0.w, a1.x,a1.y,a1.z,a1.w,
                    a2.x,a2.y,a2.z,a2.w, a3.x,a3.y,a3.z,a3.w,
                    a4.x,a4.y,a4.z,a4.w, a5.x,a5.y,a5.z,a5.w};

    // ---- per-joint constants (lanes 0..23) ----
    if (tid < NJ) {
        const int j = tid;
        float r = rpy[j*3+0], p = rpy[j*3+1], yv = rpy[j*3+2];
        float sr, cr, sp, cp, sy, cy;
        __sincosf(r, &sr, &cr);
        __sincosf(p, &sp, &cp);
        __sincosf(yv, &sy, &cy);
        float* c = &lcst[j * 16];
        c[0] = cy*cp; c[1] = cy*sp*sr - sy*cr; c[2] = cy*sp*cr + sy*sr;
        c[3] = sy*cp; c[4] = sy*sp*sr + cy*cr; c[5] = sy*sp*cr - cy*sr;
        c[6] = -sp;   c[7] = cp*sr;            c[8] = cp*cr;
        c[9]  = xyz[j*3+0]; c[10] = xyz[j*3+1]; c[11] = xyz[j*3+2];
        float ax = axis[j*3+0], ay = axis[j*3+1], az = axis[j*3+2];
        float n = sqrtf(ax*ax + ay*ay + az*az);
        float inv = 1.0f / fmaxf(n, 1e-6f);
        c[12] = ax*inv; c[13] = ay*inv; c[14] = az*inv; c[15] = n;
    }
    __syncthreads();

    // ---- FK scan state ----
    float Rp0=1.f,Rp1=0.f,Rp2=0.f,Rp3=0.f,Rp4=1.f,Rp5=0.f,Rp6=0.f,Rp7=0.f,Rp8=1.f;
    float t0=0.f, t1=0.f, t2=0.f;
    float* ob = &buf[tid * STRIDE];
    float* gO = out + b0 * OUTW;

    // one joint of the chain; writes pos into ob at column `col`
    #define STEP(j, col)                                                        \
    {                                                                           \
        const float* c = &lcst[(j) * 16];    /* wave-uniform -> broadcast */    \
        float a = th[(j)] * c[15];                                              \
        float s, ca;                                                            \
        __sincosf(a, &s, &ca);                                                  \
        float oc = 1.0f - ca;                                                   \
        float ux = c[12], uy = c[13], uz = c[14];                               \
        float xs = ux*s, ys = uy*s, zs = uz*s;                                  \
        float xo = ux*oc, yo = uy*oc, zo = uz*oc;                               \
        float R00 = ca + ux*xo, R01 = ux*yo - zs, R02 = ux*zo + ys;             \
        float R10 = uy*xo + zs, R11 = ca + uy*yo, R12 = uy*zo - xs;             \
        float R20 = uz*xo - ys, R21 = uz*yo + xs, R22 = ca + uz*zo;             \
        float x = c[9], y = c[10], z = c[11];                                   \
        t0 += Rp0*x + Rp1*y + Rp2*z;                                            \
        t1 += Rp3*x + Rp4*y + Rp5*z;                                            \
        t2 += Rp6*x + Rp7*y + Rp8*z;                                            \
        float O0=c[0],O1=c[1],O2=c[2],O3=c[3],O4=c[4],O5=c[5],O6=c[6],O7=c[7],O8=c[8]; \
        float A0 = Rp0*O0 + Rp1*O3 + Rp2*O6;                                    \
        float A1 = Rp0*O1 + Rp1*O4 + Rp2*O7;                                    \
        float A2 = Rp0*O2 + Rp1*O5 + Rp2*O8;                                    \
        float A3 = Rp3*O0 + Rp4*O3 + Rp5*O6;                                    \
        float A4 = Rp3*O1 + Rp4*O4 + Rp5*O7;                                    \
        float A5 = Rp3*O2 + Rp4*O5 + Rp5*O8;                                    \
        float A6 = Rp6*O0 + Rp7*O3 + Rp8*O6;                                    \
        float A7 = Rp6*O1 + Rp7*O4 + Rp8*O7;                                    \
        float A8 = Rp6*O2 + Rp7*O5 + Rp8*O8;                                    \
        Rp0 = A0*R00 + A1*R10 + A2*R20;                                         \
        Rp1 = A0*R01 + A1*R11 + A2*R21;                                         \
        Rp2 = A0*R02 + A1*R12 + A2*R22;                                         \
        Rp3 = A3*R00 + A4*R10 + A5*R20;                                         \
        Rp4 = A3*R01 + A4*R11 + A5*R21;                                         \
        Rp5 = A3*R02 + A4*R12 + A5*R22;                                         \
        Rp6 = A6*R00 + A7*R10 + A8*R20;                                         \
        Rp7 = A6*R01 + A7*R11 + A8*R21;                                         \
        Rp8 = A6*R02 + A7*R12 + A8*R22;                                         \
        ob[3*(col)+0] = t0;                                                     \
        ob[3*(col)+1] = t1;                                                     \
        ob[3*(col)+2] = t2;                                                     \
    }

    // ---- phase 0: base pos (zeros) + joints 0..7 -> cols 0..26 ----
    ob[0] = 0.f; ob[1] = 0.f; ob[2] = 0.f;
    #pragma unroll
    for (int j = 0; j < 8; ++j) STEP(j, j + 1);
    __syncthreads();
    dump_phase<27, 0>(buf, gO);
    __syncthreads();

    // ---- phase 1: joints 8..15 -> cols 0..23 (global cols 27..50) ----
    #pragma unroll
    for (int j = 8; j < 16; ++j) STEP(j, j - 8);
    __syncthreads();
    dump_phase<24, 27>(buf, gO);
    __syncthreads();

    // ---- phase 2: joints 16..23 -> cols 0..23 (global cols 51..74) ----
    #pragma unroll
    for (int j = 16; j < 24; ++j) STEP(j, j - 16);
    __syncthreads();
    dump_phase<24, 51>(buf, gO);

    #undef STEP
}

extern "C" void kernel_launch(void* const* d_in, const int* in_sizes, int n_in,
                              void* d_out, int out_size, void* d_ws, size_t ws_size,
                              hipStream_t stream) {
    const float* ang  = (const float*)d_in[0];
    const float* xyz  = (const float*)d_in[1];
    const float* rpy  = (const float*)d_in[2];
    const float* axis = (const float*)d_in[3];
    float* out = (float*)d_out;

    const int B = in_sizes[0] / NJ;          // 262144
    const int grid = (B + BLK - 1) / BLK;    // 2048
    fk_main_kernel<<<grid, BLK, 0, stream>>>(ang, xyz, rpy, axis, out);
}

// Round 3
// 30.210 us; speedup vs baseline: 1.7624x; 1.7624x over previous
//
#include <hip/hip_runtime.h>

#define NJ 24
#define BLK 128
#define OUTW 75              // (NJ+1)*3 floats per row
#define ROWF (BLK * OUTW)    // 9600 floats of LDS out-staging per block
#define CW 12                // per-joint constants: qA[4], qB[4], xyz[3], halfnorm

__global__ __launch_bounds__(BLK, 4) void fk_main_kernel(
    const float* __restrict__ ang,   // (B, 24)
    const float* __restrict__ xyz,   // (24, 3)
    const float* __restrict__ rpy,   // (24, 3)
    const float* __restrict__ axis,  // (24, 3)
    float* __restrict__ out)         // (B, 75)
{
    __shared__ float lcst[NJ * CW];
    __shared__ float4 buf4[ROWF / 4];    // 38.4 KB output staging (full-line dump)
    float* buf = (float*)buf4;

    const int tid = threadIdx.x;
    const long long b0 = (long long)blockIdx.x * BLK;

    // ---- my row's 24 angles via 6x float4 (row base 96B -> 16B aligned) ----
    const float4* gA4 = (const float4*)(ang + (b0 + tid) * NJ);
    float4 a0 = gA4[0], a1 = gA4[1], a2 = gA4[2], a3 = gA4[3], a4 = gA4[4], a5 = gA4[5];
    float th[NJ] = {a0.x,a0.y,a0.z,a0.w, a1.x,a1.y,a1.z,a1.w,
                    a2.x,a2.y,a2.z,a2.w, a3.x,a3.y,a3.z,a3.w,
                    a4.x,a4.y,a4.z,a4.w, a5.x,a5.y,a5.z,a5.w};

    // ---- per-joint constants (lanes 0..23): quaternionized ----
    if (tid < NJ) {
        const int j = tid;
        // qRo from ZYX euler (matches Rz(y)*Ry(p)*Rx(r) of the reference)
        float r = rpy[j*3+0] * 0.5f, p = rpy[j*3+1] * 0.5f, yv = rpy[j*3+2] * 0.5f;
        float sr, cr, sp, cp, sy, cy;
        __sincosf(r, &sr, &cr);
        __sincosf(p, &sp, &cp);
        __sincosf(yv, &sy, &cy);
        float qw = cr*cp*cy + sr*sp*sy;
        float qx = sr*cp*cy - cr*sp*sy;
        float qy = cr*sp*cy + sr*cp*sy;
        float qz = cr*cp*sy - sr*sp*cy;
        float ax = axis[j*3+0], ay = axis[j*3+1], az = axis[j*3+2];
        float n = sqrtf(ax*ax + ay*ay + az*az);
        float inv = 1.0f / fmaxf(n, 1e-6f);
        float ux = ax*inv, uy = ay*inv, uz = az*inv;
        float* c = &lcst[j * CW];
        c[0] = qw; c[1] = qx; c[2] = qy; c[3] = qz;                 // qA = qRo
        c[4] = -(qx*ux + qy*uy + qz*uz);                             // qB = qRo x (0,u)
        c[5] = qw*ux + qy*uz - qz*uy;
        c[6] = qw*uy + qz*ux - qx*uz;
        c[7] = qw*uz + qx*uy - qy*ux;
        c[8] = xyz[j*3+0]; c[9] = xyz[j*3+1]; c[10] = xyz[j*3+2];
        c[11] = n * 0.5f;                                            // half-norm
    }
    __syncthreads();

    // ---- FK scan: running orientation quaternion Q, translation t ----
    float Qw = 1.f, Qx = 0.f, Qy = 0.f, Qz = 0.f;
    float t0 = 0.f, t1 = 0.f, t2 = 0.f;
    float* ob = &buf[tid * OUTW];    // stride 75 (odd) -> conflict-free
    ob[0] = 0.f; ob[1] = 0.f; ob[2] = 0.f;

    #pragma unroll
    for (int j = 0; j < NJ; ++j) {
        const float* c = &lcst[j * CW];   // wave-uniform -> LDS broadcast
        float h = th[j] * c[11];
        float s, cq;
        __sincosf(h, &s, &cq);
        // local quaternion q = cq*qA + s*qB
        float lw = cq*c[0] + s*c[4];
        float lx = cq*c[1] + s*c[5];
        float ly = cq*c[2] + s*c[6];
        float lz = cq*c[3] + s*c[7];
        // t += rotate(Q_parent, xyz_j):  v' = v + 2*qv x (qv x v + w v)
        float vx = c[8], vy = c[9], vz = c[10];
        float px = Qy*vz - Qz*vy + Qw*vx;
        float py = Qz*vx - Qx*vz + Qw*vy;
        float pz = Qx*vy - Qy*vx + Qw*vz;
        t0 += vx + 2.0f*(Qy*pz - Qz*py);
        t1 += vy + 2.0f*(Qz*px - Qx*pz);
        t2 += vz + 2.0f*(Qx*py - Qy*px);
        // Q = Q (x) q_loc
        float nw = Qw*lw - Qx*lx - Qy*ly - Qz*lz;
        float nx = Qw*lx + Qx*lw + Qy*lz - Qz*ly;
        float ny = Qw*ly - Qx*lz + Qy*lw + Qz*lx;
        float nz = Qw*lz + Qx*ly - Qy*lx + Qz*lw;
        Qw = nw; Qx = nx; Qy = ny; Qz = nz;

        ob[3*(j+1)+0] = t0;
        ob[3*(j+1)+1] = t1;
        ob[3*(j+1)+2] = t2;
    }
    __syncthreads();

    // ---- coalesced float4 dump of the block's contiguous (128 x 75) chunk ----
    float4* gO = (float4*)(out + b0 * OUTW);   // 9600 floats -> 2400 float4
    #pragma unroll
    for (int k = 0; k < (ROWF/4 + BLK - 1) / BLK; ++k) {
        int i = tid + k * BLK;
        if (i < ROWF / 4) gO[i] = buf4[i];
    }
}

extern "C" void kernel_launch(void* const* d_in, const int* in_sizes, int n_in,
                              void* d_out, int out_size, void* d_ws, size_t ws_size,
                              hipStream_t stream) {
    const float* ang  = (const float*)d_in[0];
    const float* xyz  = (const float*)d_in[1];
    const float* rpy  = (const float*)d_in[2];
    const float* axis = (const float*)d_in[3];
    float* out = (float*)d_out;

    const int B = in_sizes[0] / NJ;          // 262144
    const int grid = (B + BLK - 1) / BLK;    // 2048
    fk_main_kernel<<<grid, BLK, 0, stream>>>(ang, xyz, rpy, axis, out);
}

// Round 4
// 28.576 us; speedup vs baseline: 1.8632x; 1.0572x over previous
//
#include <hip/hip_runtime.h>

#define NJ 24
#define BLK 128
#define OUTW 75               // (NJ+1)*3 floats per row
#define WROWS 64              // rows per wave
#define WBUF (WROWS * OUTW)   // 4800 floats per wave region
#define CPB 2                 // chunks per block (grid-stride pipeline)
#define CW 12                 // per-joint consts: qA[4], qB[4], xyz[3], halfnorm

__global__ __launch_bounds__(BLK, 2) void fk_main_kernel(
    const float* __restrict__ ang,   // (B, 24)
    const float* __restrict__ xyz,   // (24, 3)
    const float* __restrict__ rpy,   // (24, 3)
    const float* __restrict__ axis,  // (24, 3)
    float* __restrict__ out)         // (B, 75)
{
    __shared__ float lcst[NJ * CW];
    __shared__ float buf[(BLK / 64) * WBUF];   // 2 x 19.2 KB per-wave staging

    const int tid = threadIdx.x;
    const int wv = tid >> 6, ln = tid & 63;
    float* wbuf = &buf[wv * WBUF];

    const long long chunk0 = (long long)blockIdx.x * CPB;

    // ---- issue chunk0 angle loads early (row base 96B -> 16B aligned) ----
    const float4* gA = (const float4*)(ang + (chunk0 * BLK + tid) * NJ);
    float4 A0 = gA[0], A1 = gA[1], A2 = gA[2], A3 = gA[3], A4 = gA[4], A5 = gA[5];

    // ---- per-joint constants (lanes 0..23): quaternionized ----
    if (tid < NJ) {
        const int j = tid;
        float r = rpy[j*3+0] * 0.5f, p = rpy[j*3+1] * 0.5f, yv = rpy[j*3+2] * 0.5f;
        float sr, cr, sp, cp, sy, cy;
        __sincosf(r, &sr, &cr);
        __sincosf(p, &sp, &cp);
        __sincosf(yv, &sy, &cy);
        float qw = cr*cp*cy + sr*sp*sy;
        float qx = sr*cp*cy - cr*sp*sy;
        float qy = cr*sp*cy + sr*cp*sy;
        float qz = cr*cp*sy - sr*sp*cy;
        float ax = axis[j*3+0], ay = axis[j*3+1], az = axis[j*3+2];
        float n = sqrtf(ax*ax + ay*ay + az*az);
        float inv = 1.0f / fmaxf(n, 1e-6f);
        float ux = ax*inv, uy = ay*inv, uz = az*inv;
        float* c = &lcst[j * CW];
        c[0] = qw; c[1] = qx; c[2] = qy; c[3] = qz;         // qA = qRo
        c[4] = -(qx*ux + qy*uy + qz*uz);                     // qB = qRo x (0,u)
        c[5] = qw*ux + qy*uz - qz*uy;
        c[6] = qw*uy + qz*ux - qx*uz;
        c[7] = qw*uz + qx*uy - qy*ux;
        c[8] = xyz[j*3+0]; c[9] = xyz[j*3+1]; c[10] = xyz[j*3+2];
        c[11] = n * 0.5f;
    }
    __syncthreads();   // once, before any global stores -> drain is cheap

    #pragma unroll
    for (int c = 0; c < CPB; ++c) {
        float th[NJ] = {A0.x,A0.y,A0.z,A0.w, A1.x,A1.y,A1.z,A1.w,
                        A2.x,A2.y,A2.z,A2.w, A3.x,A3.y,A3.z,A3.w,
                        A4.x,A4.y,A4.z,A4.w, A5.x,A5.y,A5.z,A5.w};

        if (c) {
            // WAR guard: all of previous dump's ds_reads complete before
            // overwriting the wave's staging region. No vmcnt drain here:
            // previous chunk's global stores stay in flight.
            asm volatile("s_waitcnt lgkmcnt(0)" ::: "memory");
            __builtin_amdgcn_sched_barrier(0);
        }

        // ---- FK scan: quaternion chain, stage positions in own wave region ----
        float Qw = 1.f, Qx = 0.f, Qy = 0.f, Qz = 0.f;
        float t0 = 0.f, t1 = 0.f, t2 = 0.f;
        float* ob = wbuf + ln * OUTW;    // stride 75 (odd) -> conflict-free
        ob[0] = 0.f; ob[1] = 0.f; ob[2] = 0.f;

        #pragma unroll
        for (int j = 0; j < NJ; ++j) {
            const float* cc = &lcst[j * CW];   // wave-uniform -> LDS broadcast
            float h = th[j] * cc[11];
            float s, cq;
            __sincosf(h, &s, &cq);
            float lw = cq*cc[0] + s*cc[4];
            float lx = cq*cc[1] + s*cc[5];
            float ly = cq*cc[2] + s*cc[6];
            float lz = cq*cc[3] + s*cc[7];
            float vx = cc[8], vy = cc[9], vz = cc[10];
            float px = Qy*vz - Qz*vy + Qw*vx;
            float py = Qz*vx - Qx*vz + Qw*vy;
            float pz = Qx*vy - Qy*vx + Qw*vz;
            t0 += vx + 2.0f*(Qy*pz - Qz*py);
            t1 += vy + 2.0f*(Qz*px - Qx*pz);
            t2 += vz + 2.0f*(Qx*py - Qy*px);
            float nw = Qw*lw - Qx*lx - Qy*ly - Qz*lz;
            float nx = Qw*lx + Qx*lw + Qy*lz - Qz*ly;
            float ny = Qw*ly - Qx*lz + Qy*lw + Qz*lx;
            float nz = Qw*lz + Qx*ly - Qy*lx + Qz*lw;
            Qw = nw; Qx = nx; Qy = ny; Qz = nz;
            ob[3*(j+1)+0] = t0;
            ob[3*(j+1)+1] = t1;
            ob[3*(j+1)+2] = t2;
        }

        // ---- prefetch next chunk's angles (hides under the dump stores) ----
        if (c + 1 < CPB) {
            const float4* gN = (const float4*)(ang + ((chunk0 + c + 1) * BLK + tid) * NJ);
            A0 = gN[0]; A1 = gN[1]; A2 = gN[2]; A3 = gN[3]; A4 = gN[4]; A5 = gN[5];
        }

        // ---- stage visible to whole wave (wave-lockstep + lgkm drain) ----
        asm volatile("s_waitcnt lgkmcnt(0)" ::: "memory");
        __builtin_amdgcn_sched_barrier(0);

        // ---- per-wave coalesced dump: 1200 float4 = 19200B contiguous ----
        float4* gO = (float4*)(out + (chunk0 + c) * (BLK * OUTW)) + wv * (WBUF / 4);
        const float4* lb = (const float4*)wbuf;
        #pragma unroll
        for (int k = 0; k < 19; ++k) {
            int i = k * 64 + ln;
            if (i < WBUF / 4) gO[i] = lb[i];
        }
    }
}

extern "C" void kernel_launch(void* const* d_in, const int* in_sizes, int n_in,
                              void* d_out, int out_size, void* d_ws, size_t ws_size,
                              hipStream_t stream) {
    const float* ang  = (const float*)d_in[0];
    const float* xyz  = (const float*)d_in[1];
    const float* rpy  = (const float*)d_in[2];
    const float* axis = (const float*)d_in[3];
    float* out = (float*)d_out;

    const int B = in_sizes[0] / NJ;                  // 262144
    const int grid = B / (BLK * CPB);                // 1024 = 4 blocks/CU, one round
    fk_main_kernel<<<grid, BLK, 0, stream>>>(ang, xyz, rpy, axis, out);
}